// Round 1
// baseline (116.849 us; speedup 1.0000x reference)
//
#include <hip/hip_runtime.h>
#include <hip/hip_bf16.h>

#define HDIM 2048
#define HH (HDIM * HDIM)          // 4,194,304 pixels per plane
#define NBINS 256
#define KCNT 1048576.0f           // K_SRC == K_TAR == HH/4 (exactly 2^20)
#define TOTAL_ELEMS 12582912.0    // 3 * H * H

// ws layout:
//   [0, 6144)      : int   hists[6][256]   (ch0..2 = dst/src, ch3..5 = ref/tar)
//   [6144, 9216)   : float tables[3][256]
//   [9216, 9224)   : double accumulator
#define WS_HIST_OFF   0
#define WS_TABLE_OFF  6144
#define WS_ACC_OFF    9216
#define WS_ZERO_BYTES 9224

__device__ __forceinline__ float de_norm255(float x) {
    float v = (x + 1.0f) * 0.5f;               // /2.0 == *0.5 exactly in f32
    v = fminf(fmaxf(v, 0.0f), 1.0f) * 255.0f;  // in [0, 255]
    return v;
}

__device__ __forceinline__ int bin_of(float v255) {
    int b = (int)v255;            // truncation; v255 >= 0
    return b > 255 ? 255 : b;
}

// Kernel 1: build 6 histograms (3 channels x {src-masked input, tar-masked target})
__global__ void hist_kernel(const float* __restrict__ inp,
                            const float* __restrict__ tar,
                            const float* __restrict__ msrc,
                            const float* __restrict__ mtar,
                            int* __restrict__ hists) {
    __shared__ int lh[6 * NBINS];
    for (int i = threadIdx.x; i < 6 * NBINS; i += blockDim.x) lh[i] = 0;
    __syncthreads();

    const int stride = gridDim.x * blockDim.x;
    const int n4 = HH / 4;
    for (int p4 = blockIdx.x * blockDim.x + threadIdx.x; p4 < n4; p4 += stride) {
        float4 ms4 = ((const float4*)msrc)[p4];
        float4 mt4 = ((const float4*)mtar)[p4];
        float m[4] = {ms4.x, ms4.y, ms4.z, ms4.w};
        float t[4] = {mt4.x, mt4.y, mt4.z, mt4.w};
        #pragma unroll
        for (int c = 0; c < 3; ++c) {
            float4 v4 = ((const float4*)(inp + (size_t)c * HH))[p4];
            float4 w4 = ((const float4*)(tar + (size_t)c * HH))[p4];
            float vv[4] = {v4.x, v4.y, v4.z, v4.w};
            float ww[4] = {w4.x, w4.y, w4.z, w4.w};
            #pragma unroll
            for (int k = 0; k < 4; ++k) {
                if (m[k] != 0.0f) {
                    int b = bin_of(de_norm255(vv[k]));
                    atomicAdd(&lh[c * NBINS + b], 1);
                }
                if (t[k] != 0.0f) {
                    int b = bin_of(de_norm255(ww[k]));
                    atomicAdd(&lh[(3 + c) * NBINS + b], 1);
                }
            }
        }
    }
    __syncthreads();
    for (int i = threadIdx.x; i < 6 * NBINS; i += blockDim.x) {
        int v = lh[i];
        if (v) atomicAdd(&hists[i], v);
    }
}

// Kernel 2: CDFs (sequential f32 cumsum, matching the reference) + mapping tables
__global__ void table_kernel(const int* __restrict__ hists,
                             float* __restrict__ tables) {
    const int c = blockIdx.x;   // channel 0..2
    __shared__ float dcdf[NBINS];
    __shared__ float rcdf[NBINS];
    if (threadIdx.x == 0) {
        // pdf = count / 2^20 is EXACT (power-of-two divide); cumsum sequential f32
        float run = 0.0f;
        for (int i = 0; i < NBINS; ++i) {
            run += (float)hists[c * NBINS + i] * (1.0f / KCNT);
            dcdf[i] = run;
        }
        run = 0.0f;
        for (int i = 0; i < NBINS; ++i) {
            run += (float)hists[(3 + c) * NBINS + i] * (1.0f / KCNT);
            rcdf[i] = run;
        }
    }
    __syncthreads();

    const int i = threadIdx.x;
    float d = dcdf[i];
    // searchsorted(rcdf, d, side='left'): first j with rcdf[j] >= d
    int lo = 0, hi = NBINS;
    while (lo < hi) {
        int mid = (lo + hi) >> 1;
        if (rcdf[mid] < d) lo = mid + 1; else hi = mid;
    }
    int j = lo;
    if (j < 1) j = 1;
    if (j > NBINS - 1) j = NBINS - 1;
    bool valid = (rcdf[j - 1] <= d) && (d <= rcdf[j]);
    int t = valid ? j : i;
    if (i == NBINS - 1) t = NBINS - 1;
    tables[c * NBINS + i] = (float)t;
}

// Kernel 3: sum |v - table[bin(v)]| over masked src pixels, all 3 channels
__global__ void loss_kernel(const float* __restrict__ inp,
                            const float* __restrict__ msrc,
                            const float* __restrict__ tables,
                            double* __restrict__ acc) {
    __shared__ float tl[3 * NBINS];
    for (int i = threadIdx.x; i < 3 * NBINS; i += blockDim.x)
        tl[i] = tables[i];
    __syncthreads();

    float s = 0.0f;
    const int stride = gridDim.x * blockDim.x;
    const int n4 = HH / 4;
    for (int p4 = blockIdx.x * blockDim.x + threadIdx.x; p4 < n4; p4 += stride) {
        float4 ms4 = ((const float4*)msrc)[p4];
        float m[4] = {ms4.x, ms4.y, ms4.z, ms4.w};
        if (m[0] == 0.0f && m[1] == 0.0f && m[2] == 0.0f && m[3] == 0.0f) continue;
        #pragma unroll
        for (int c = 0; c < 3; ++c) {
            float4 v4 = ((const float4*)(inp + (size_t)c * HH))[p4];
            float vv[4] = {v4.x, v4.y, v4.z, v4.w};
            #pragma unroll
            for (int k = 0; k < 4; ++k) {
                if (m[k] != 0.0f) {
                    float v = de_norm255(vv[k]);
                    int b = bin_of(v);
                    s += fabsf(v - tl[c * NBINS + b]);
                }
            }
        }
    }

    // wave64 reduce
    #pragma unroll
    for (int off = 32; off > 0; off >>= 1)
        s += __shfl_down(s, off, 64);

    __shared__ float wsum[4];    // up to 256 threads = 4 waves
    const int wave = threadIdx.x >> 6;
    const int lane = threadIdx.x & 63;
    if (lane == 0) wsum[wave] = s;
    __syncthreads();
    if (threadIdx.x == 0) {
        double bs = 0.0;
        const int nw = blockDim.x >> 6;
        for (int w = 0; w < nw; ++w) bs += (double)wsum[w];
        atomicAdd(acc, bs);
    }
}

__global__ void finalize_kernel(const double* __restrict__ acc,
                                float* __restrict__ out) {
    out[0] = (float)(acc[0] / TOTAL_ELEMS);
}

extern "C" void kernel_launch(void* const* d_in, const int* in_sizes, int n_in,
                              void* d_out, int out_size, void* d_ws, size_t ws_size,
                              hipStream_t stream) {
    const float* inp  = (const float*)d_in[0];   // (1,3,H,H)
    const float* tar  = (const float*)d_in[1];   // (1,3,H,H)
    const float* msrc = (const float*)d_in[2];   // (1,1,H,H)
    const float* mtar = (const float*)d_in[3];   // (1,1,H,H)
    float* out = (float*)d_out;

    char* ws = (char*)d_ws;
    int*    hists  = (int*)(ws + WS_HIST_OFF);
    float*  tables = (float*)(ws + WS_TABLE_OFF);
    double* acc    = (double*)(ws + WS_ACC_OFF);

    // re-zero scratch every call (graph-capturable, deterministic replays)
    hipMemsetAsync(d_ws, 0, WS_ZERO_BYTES, stream);

    const int threads = 256;
    const int blocks = 2048;
    hist_kernel<<<blocks, threads, 0, stream>>>(inp, tar, msrc, mtar, hists);
    table_kernel<<<3, NBINS, 0, stream>>>(hists, tables);
    loss_kernel<<<blocks, threads, 0, stream>>>(inp, msrc, tables, acc);
    finalize_kernel<<<1, 1, 0, stream>>>(acc, out);
}